// Round 2
// baseline (1369.943 us; speedup 1.0000x reference)
//
#include <hip/hip_runtime.h>
#include <hip/hip_bf16.h>

// B=4096, T=64, P=64, H1=H2=512. Per-t MLP with training-mode BatchNorm.
// BN stats are per-(t,feature) over B -> timesteps are independent -> process
// T in chunks of TC=8 so only the chunk's h1/h2 (32 MB each) are live in ws.
// BN0 folded into W1/b1. BN1/BN2 stats accumulated from fp32 MFMA accumulators
// via atomics in the GEMM epilogue; BN+ReLU applied in the NEXT GEMM's
// A-staging. Weights pre-transposed+cast to [T,N,K] bf16.
// Total ws use ~105 MB (guarded).

#define B_ 4096
#define T_ 64
#define P_ 64
#define H1_ 512
#define H2_ 512
#define TC_ 8
#define BN_EPS 1e-3f

typedef float f32x4 __attribute__((ext_vector_type(4)));
typedef short s16x8 __attribute__((ext_vector_type(8)));
typedef unsigned short u16;
typedef unsigned short u16x8 __attribute__((ext_vector_type(8)));

__device__ __forceinline__ u16 f2bf(float f) {
  union { float f; unsigned u; } x; x.f = f;
  unsigned r = x.u + 0x7fffu + ((x.u >> 16) & 1u);  // RNE
  return (u16)(r >> 16);
}
__device__ __forceinline__ float bf2f(u16 h) {
  union { unsigned u; float f; } x; x.u = ((unsigned)h) << 16;
  return x.f;
}

// ---- BN0 batch stats over prices (per t,p over B) ----
__global__ void stats0_k(const float* __restrict__ x, float* __restrict__ sum,
                         float* __restrict__ sq) {
  const int t = blockIdx.x;
  const int chunk = blockIdx.y;  // 8 chunks over B
  const int tid = threadIdx.x;   // 256
  const int p = tid & 63;
  const int bs = tid >> 6;       // 0..3
  float s = 0.f, q = 0.f;
  const int b0 = chunk * (B_ / 8), bend = b0 + (B_ / 8);
  for (int b = b0 + bs; b < bend; b += 4) {
    float v = x[((size_t)b * T_ + t) * P_ + p];
    s += v; q += v * v;
  }
  __shared__ float ls[4][64], lq[4][64];
  ls[bs][p] = s; lq[bs][p] = q;
  __syncthreads();
  if (tid < 64) {
    float S = ls[0][tid] + ls[1][tid] + ls[2][tid] + ls[3][tid];
    float Q = lq[0][tid] + lq[1][tid] + lq[2][tid] + lq[3][tid];
    atomicAdd(&sum[t * P_ + tid], S);
    atomicAdd(&sq[t * P_ + tid], Q);
  }
}

// ---- finalize BN affine: s = g*rsqrt(var+eps), sh = b - mean*s ----
__global__ void finalize_k(const float* __restrict__ sum, const float* __restrict__ sq,
                           const float* __restrict__ g, const float* __restrict__ b,
                           float* __restrict__ s, float* __restrict__ sh, int n) {
  int i = blockIdx.x * 256 + threadIdx.x;
  if (i >= n) return;
  float m = sum[i] * (1.f / B_);
  float v = sq[i] * (1.f / B_) - m * m;
  float sc = g[i] * rsqrtf(v + BN_EPS);
  s[i] = sc;
  sh[i] = b[i] - m * sc;
}

// ---- fold BN0 into W1: W1t[t,h,p] = bf16(s0[t,p]*W1[t,p,h]); b1p = b1 + sh0@W1 ----
__global__ void fold1_k(const float* __restrict__ W1, const float* __restrict__ b1,
                        const float* __restrict__ s0, const float* __restrict__ sh0,
                        u16* __restrict__ W1t, float* __restrict__ b1p) {
  const int t = blockIdx.x;
  const int h = blockIdx.y * 256 + threadIdx.x;
  float acc = b1[t * H1_ + h];
  for (int p = 0; p < P_; ++p) {
    float w = W1[((size_t)t * P_ + p) * H1_ + h];
    acc += sh0[t * P_ + p] * w;
    W1t[((size_t)t * H1_ + h) * P_ + p] = f2bf(w * s0[t * P_ + p]);
  }
  b1p[t * H1_ + h] = acc;
}

// ---- transpose+cast weights: Wt[t,n,k] = bf16(W[t,k,n]) ----
template <int KD, int ND>
__global__ void castWT_k(const float* __restrict__ W, u16* __restrict__ Wt) {
  const int t = blockIdx.z;
  const int kb = blockIdx.y * 64;
  const int nb = blockIdx.x * 64;
  __shared__ float tile[64][65];
  const int tid = threadIdx.x;
  {
    const int n = tid & 63, k0 = tid >> 6;
    for (int i = k0; i < 64; i += 4)
      tile[i][n] = W[((size_t)t * KD + kb + i) * ND + nb + n];
  }
  __syncthreads();
  {
    const int k = tid & 63, n0 = tid >> 6;
    for (int j = n0; j < 64; j += 4)
      Wt[((size_t)t * ND + nb + j) * KD + kb + k] = f2bf(tile[k][j]);
  }
}

// ---- MFMA GEMM over a T-chunk: C[b,tz,n] = act_bn(A[b,tz,:]) @ Bt[tg,n,:] + bias[tg,n]
// A: [B, TA, K] (f32 or bf16); Bt: [T, N, K] bf16. tg = t0 + blockIdx.z (global t),
// A/Out index with local tz if *_LOCAL. Optional pre-BN+relu on A in staging;
// optional per-column stats atomics on fp32 result (post-bias, pre-round).
template <int K_DIM, int N_DIM, int BM, int BN, int BK, int WM, int WN,
          int TA, int TO, bool A_F32, bool PRE_BN, bool STATS, bool OUT_F32,
          bool A_LOCAL, bool O_LOCAL>
__global__ __launch_bounds__(256) void gemm_k(
    const void* __restrict__ Av, const u16* __restrict__ Bt,
    const float* __restrict__ bias, const float* __restrict__ ps,
    const float* __restrict__ ph, void* __restrict__ Out,
    float* __restrict__ osum, float* __restrict__ osq, int t0) {
  constexpr int WTM = BM / WM, WTN = BN / WN;
  constexpr int FM = WTM / 16, FN = WTN / 16;
  constexpr int LDK = BK + 8;  // +8 bf16 pad -> ~2-way frag-read conflict (free)
  __shared__ __align__(16) u16 As[BM][LDK];
  __shared__ __align__(16) u16 Bs[BN][LDK];

  const int tz = blockIdx.z;
  const int tg = t0 + tz;
  const int ta = A_LOCAL ? tz : tg;
  const int to = O_LOCAL ? tz : tg;
  const int brow0 = blockIdx.y * BM;
  const int bcol0 = blockIdx.x * BN;
  const int tid = threadIdx.x;
  const int lane = tid & 63;
  const int wid = tid >> 6;
  const int wm = wid / WN, wn = wid % WN;

  f32x4 acc[FM][FN] = {};

  for (int k0 = 0; k0 < K_DIM; k0 += BK) {
    // stage A (BM x BK), reg-staged (dtype cast + fused BN/relu)
    for (int c = tid; c < BM * BK / 8; c += 256) {
      const int row = c / (BK / 8);
      const int col = (c % (BK / 8)) * 8;
      const size_t goff = ((size_t)(brow0 + row) * TA + ta) * K_DIM + k0 + col;
      float fv[8];
      u16x8 v;
      if constexpr (A_F32) {
        const float* src = (const float*)Av + goff;
        const float4 u0 = *(const float4*)src;
        const float4 u1 = *(const float4*)(src + 4);
        fv[0] = u0.x; fv[1] = u0.y; fv[2] = u0.z; fv[3] = u0.w;
        fv[4] = u1.x; fv[5] = u1.y; fv[6] = u1.z; fv[7] = u1.w;
      } else {
        v = *(const u16x8*)((const u16*)Av + goff);
        if constexpr (PRE_BN) {
#pragma unroll
          for (int j = 0; j < 8; ++j) fv[j] = bf2f(v[j]);
        }
      }
      if constexpr (PRE_BN) {
        const float* psp = ps + (size_t)tg * K_DIM + k0 + col;
        const float* php = ph + (size_t)tg * K_DIM + k0 + col;
#pragma unroll
        for (int j = 0; j < 8; ++j) fv[j] = fmaxf(fv[j] * psp[j] + php[j], 0.f);
      }
      if constexpr (A_F32 || PRE_BN) {
#pragma unroll
        for (int j = 0; j < 8; ++j) v[j] = f2bf(fv[j]);
      }
      *(u16x8*)&As[row][col] = v;
    }
    // stage B (BN x BK) from pre-transposed [T,N,K]
    for (int c = tid; c < BN * BK / 8; c += 256) {
      const int row = c / (BK / 8);
      const int col = (c % (BK / 8)) * 8;
      *(u16x8*)&Bs[row][col] =
          *(const u16x8*)(Bt + ((size_t)tg * N_DIM + bcol0 + row) * K_DIM + k0 + col);
    }
    __syncthreads();
#pragma unroll
    for (int ks = 0; ks < BK / 32; ++ks) {
      s16x8 aF[FM], bF[FN];
#pragma unroll
      for (int m = 0; m < FM; ++m)
        aF[m] = *(const s16x8*)&As[wm * WTM + m * 16 + (lane & 15)]
                                  [ks * 32 + (lane >> 4) * 8];
#pragma unroll
      for (int n = 0; n < FN; ++n)
        bF[n] = *(const s16x8*)&Bs[wn * WTN + n * 16 + (lane & 15)]
                                  [ks * 32 + (lane >> 4) * 8];
#pragma unroll
      for (int m = 0; m < FM; ++m)
#pragma unroll
        for (int n = 0; n < FN; ++n)
          acc[m][n] = __builtin_amdgcn_mfma_f32_16x16x32_bf16(aF[m], bF[n],
                                                              acc[m][n], 0, 0, 0);
    }
    __syncthreads();
  }

  // epilogue: C/D layout col=lane&15, row=(lane>>4)*4+r (m89-verified)
  const int r0 = (lane >> 4) * 4;
  const int cl = lane & 15;
#pragma unroll
  for (int n = 0; n < FN; ++n) {
    const int ncol = bcol0 + wn * WTN + n * 16 + cl;
    const float bv = bias[(size_t)tg * N_DIM + ncol];
    float csum = 0.f, csq = 0.f;
#pragma unroll
    for (int m = 0; m < FM; ++m) {
      const int rbase = brow0 + wm * WTM + m * 16 + r0;
#pragma unroll
      for (int r = 0; r < 4; ++r) {
        const float h = acc[m][n][r] + bv;
        if constexpr (STATS) { csum += h; csq += h * h; }
        const size_t oidx = ((size_t)(rbase + r) * TO + to) * N_DIM + ncol;
        if constexpr (OUT_F32) ((float*)Out)[oidx] = h;
        else                   ((u16*)Out)[oidx] = f2bf(h);
      }
    }
    if constexpr (STATS) {
      csum += __shfl_xor(csum, 16);
      csum += __shfl_xor(csum, 32);
      csq += __shfl_xor(csq, 16);
      csq += __shfl_xor(csq, 32);
      if (lane < 16) {
        atomicAdd(&osum[(size_t)tg * N_DIM + ncol], csum);
        atomicAdd(&osq[(size_t)tg * N_DIM + ncol], csq);
      }
    }
  }
}

extern "C" void kernel_launch(void* const* d_in, const int* in_sizes, int n_in,
                              void* d_out, int out_size, void* d_ws, size_t ws_size,
                              hipStream_t stream) {
  const float* prices = (const float*)d_in[0];
  const float* bn0_g = (const float*)d_in[1];
  const float* bn0_b = (const float*)d_in[2];
  const float* W1 = (const float*)d_in[3];
  const float* b1 = (const float*)d_in[4];
  const float* bn1_g = (const float*)d_in[5];
  const float* bn1_b = (const float*)d_in[6];
  const float* W2 = (const float*)d_in[7];
  const float* b2 = (const float*)d_in[8];
  const float* bn2_g = (const float*)d_in[9];
  const float* bn2_b = (const float*)d_in[10];
  const float* W3 = (const float*)d_in[11];
  const float* b3 = (const float*)d_in[12];
  (void)in_sizes; (void)n_in; (void)out_size;

  // diagnostic guard: needed ws ~105.3 MB. If ws is smaller, do nothing ->
  // bench reports stub-signature absmax (~4.65) instead of crashing.
  if (ws_size < 115343360ull) return;

  char* ws = (char*)d_ws;
  size_t off = 0;
  auto alloc = [&](size_t bytes) -> void* {
    void* p = ws + off;
    off += (bytes + 255) & ~(size_t)255;
    return p;
  };
  // stats accumulators first (contiguous -> one memset)
  float* sum0 = (float*)alloc(T_ * P_ * 4);
  float* sq0 = (float*)alloc(T_ * P_ * 4);
  float* sum1 = (float*)alloc(T_ * H1_ * 4);
  float* sq1 = (float*)alloc(T_ * H1_ * 4);
  float* sum2 = (float*)alloc(T_ * H2_ * 4);
  float* sq2 = (float*)alloc(T_ * H2_ * 4);
  const size_t statsBytes = off;
  float* s0 = (float*)alloc(T_ * P_ * 4);
  float* sh0 = (float*)alloc(T_ * P_ * 4);
  float* s1 = (float*)alloc(T_ * H1_ * 4);
  float* sh1 = (float*)alloc(T_ * H1_ * 4);
  float* s2 = (float*)alloc(T_ * H2_ * 4);
  float* sh2 = (float*)alloc(T_ * H2_ * 4);
  float* b1p = (float*)alloc(T_ * H1_ * 4);
  u16* W1t = (u16*)alloc((size_t)T_ * H1_ * P_ * 2);        //  4 MB
  u16* W2t = (u16*)alloc((size_t)T_ * H1_ * H2_ * 2);       // 32 MB
  u16* W3t = (u16*)alloc((size_t)T_ * H2_ * P_ * 2);        //  4 MB
  u16* h1c = (u16*)alloc((size_t)B_ * TC_ * H1_ * 2);       // 32 MB
  u16* h2c = (u16*)alloc((size_t)B_ * TC_ * H2_ * 2);       // 32 MB

  hipMemsetAsync(d_ws, 0, statsBytes, stream);

  stats0_k<<<dim3(T_, 8), 256, 0, stream>>>(prices, sum0, sq0);
  finalize_k<<<(T_ * P_ + 255) / 256, 256, 0, stream>>>(sum0, sq0, bn0_g, bn0_b,
                                                        s0, sh0, T_ * P_);
  fold1_k<<<dim3(T_, H1_ / 256), 256, 0, stream>>>(W1, b1, s0, sh0, W1t, b1p);
  castWT_k<H1_, H2_><<<dim3(H2_ / 64, H1_ / 64, T_), 256, 0, stream>>>(W2, W2t);
  castWT_k<H2_, P_><<<dim3(P_ / 64, H2_ / 64, T_), 256, 0, stream>>>(W3, W3t);

  for (int c = 0; c < T_ / TC_; ++c) {
    const int t0 = c * TC_;
    // GEMM1: prices(f32, global t) @ W1t + b1' -> h1c (bf16, local t) + bn1 stats
    gemm_k<P_, H1_, 128, 128, 64, 2, 2, T_, TC_, true, false, true, false, false, true>
        <<<dim3(H1_ / 128, B_ / 128, TC_), 256, 0, stream>>>(
            prices, W1t, b1p, nullptr, nullptr, h1c, sum1, sq1, t0);
    finalize_k<<<(TC_ * H1_) / 256, 256, 0, stream>>>(
        sum1 + t0 * H1_, sq1 + t0 * H1_, bn1_g + t0 * H1_, bn1_b + t0 * H1_,
        s1 + t0 * H1_, sh1 + t0 * H1_, TC_ * H1_);
    // GEMM2: relu(h1c*s1+sh1) @ W2t + b2 -> h2c (bf16, local t) + bn2 stats
    gemm_k<H1_, H2_, 128, 128, 64, 2, 2, TC_, TC_, false, true, true, false, true, true>
        <<<dim3(H2_ / 128, B_ / 128, TC_), 256, 0, stream>>>(
            h1c, W2t, b2, s1, sh1, h2c, sum2, sq2, t0);
    finalize_k<<<(TC_ * H2_) / 256, 256, 0, stream>>>(
        sum2 + t0 * H2_, sq2 + t0 * H2_, bn2_g + t0 * H2_, bn2_b + t0 * H2_,
        s2 + t0 * H2_, sh2 + t0 * H2_, TC_ * H2_);
    // GEMM3: relu(h2c*s2+sh2) @ W3t + b3 -> out (f32, global t)
    gemm_k<H2_, P_, 128, 64, 64, 4, 1, TC_, T_, false, true, false, true, true, false>
        <<<dim3(P_ / 64, B_ / 128, TC_), 256, 0, stream>>>(
            h2c, W3t, b3, s2, sh2, d_out, nullptr, nullptr, t0);
  }
}

// Round 5
// 834.263 us; speedup vs baseline: 1.6421x; 1.6421x over previous
//
#include <hip/hip_runtime.h>
#include <hip/hip_bf16.h>

// B=4096, T=64, P=64, H1=H2=512. Per-t MLP with training-mode BatchNorm.
// T processed in chunks of TC=8 (BN stats independent per t) -> h1/h2 live
// only as 32 MB chunk buffers. BN0 folded into W1/b1. BN1/BN2 stats from fp32
// MFMA accumulators via epilogue atomics; BN finalize (rsqrt) computed in the
// consuming GEMM's prologue; BN+ReLU applied in its A-staging.
// GEMM structure: reg-prefetch (T14 async-stage split) + per-t XCD mapping
// (tz = bid % 8) so producer-written h1c/h2c t-slices (4 MB = one XCD L2)
// are consumed from the same XCD's L2.

#define B_ 4096
#define T_ 64
#define P_ 64
#define H1_ 512
#define H2_ 512
#define TC_ 8
#define BN_EPS 1e-3f

typedef float f32x4 __attribute__((ext_vector_type(4)));
typedef short s16x8 __attribute__((ext_vector_type(8)));
typedef unsigned short u16;
typedef unsigned short u16x8 __attribute__((ext_vector_type(8)));

__device__ __forceinline__ u16 f2bf(float f) {
  union { float f; unsigned u; } x; x.f = f;
  unsigned r = x.u + 0x7fffu + ((x.u >> 16) & 1u);  // RNE
  return (u16)(r >> 16);
}
__device__ __forceinline__ float bf2f(u16 h) {
  union { unsigned u; float f; } x; x.u = ((unsigned)h) << 16;
  return x.f;
}

// ---- BN0 batch stats over prices (per t,p over B) ----
__global__ void stats0_k(const float* __restrict__ x, float* __restrict__ sum,
                         float* __restrict__ sq) {
  const int t = blockIdx.x;
  const int chunk = blockIdx.y;  // 8 chunks over B
  const int tid = threadIdx.x;   // 256
  const int p = tid & 63;
  const int bs = tid >> 6;       // 0..3
  float s = 0.f, q = 0.f;
  const int b0 = chunk * (B_ / 8), bend = b0 + (B_ / 8);
  for (int b = b0 + bs; b < bend; b += 4) {
    float v = x[((size_t)b * T_ + t) * P_ + p];
    s += v; q += v * v;
  }
  __shared__ float ls[4][64], lq[4][64];
  ls[bs][p] = s; lq[bs][p] = q;
  __syncthreads();
  if (tid < 64) {
    float S = ls[0][tid] + ls[1][tid] + ls[2][tid] + ls[3][tid];
    float Q = lq[0][tid] + lq[1][tid] + lq[2][tid] + lq[3][tid];
    atomicAdd(&sum[t * P_ + tid], S);
    atomicAdd(&sq[t * P_ + tid], Q);
  }
}

// ---- finalize BN0 affine: s = g*rsqrt(var+eps), sh = b - mean*s ----
__global__ void finalize_k(const float* __restrict__ sum, const float* __restrict__ sq,
                           const float* __restrict__ g, const float* __restrict__ b,
                           float* __restrict__ s, float* __restrict__ sh, int n) {
  int i = blockIdx.x * 256 + threadIdx.x;
  if (i >= n) return;
  float m = sum[i] * (1.f / B_);
  float v = sq[i] * (1.f / B_) - m * m;
  float sc = g[i] * rsqrtf(v + BN_EPS);
  s[i] = sc;
  sh[i] = b[i] - m * sc;
}

// ---- fold BN0 into W1: W1t[t,h,p] = bf16(s0[t,p]*W1[t,p,h]); b1p = b1 + sh0@W1 ----
__global__ void fold1_k(const float* __restrict__ W1, const float* __restrict__ b1,
                        const float* __restrict__ s0, const float* __restrict__ sh0,
                        u16* __restrict__ W1t, float* __restrict__ b1p) {
  const int t = blockIdx.x;
  const int h = blockIdx.y * 256 + threadIdx.x;
  float acc = b1[t * H1_ + h];
  for (int p = 0; p < P_; ++p) {
    float w = W1[((size_t)t * P_ + p) * H1_ + h];
    acc += sh0[t * P_ + p] * w;
    W1t[((size_t)t * H1_ + h) * P_ + p] = f2bf(w * s0[t * P_ + p]);
  }
  b1p[t * H1_ + h] = acc;
}

// ---- transpose+cast weights: Wt[t,n,k] = bf16(W[t,k,n]) ----
template <int KD, int ND>
__global__ void castWT_k(const float* __restrict__ W, u16* __restrict__ Wt) {
  const int t = blockIdx.z;
  const int kb = blockIdx.y * 64;
  const int nb = blockIdx.x * 64;
  __shared__ float tile[64][65];
  const int tid = threadIdx.x;
  {
    const int n = tid & 63, k0 = tid >> 6;
    for (int i = k0; i < 64; i += 4)
      tile[i][n] = W[((size_t)t * KD + kb + i) * ND + nb + n];
  }
  __syncthreads();
  {
    const int k = tid & 63, n0 = tid >> 6;
    for (int j = n0; j < 64; j += 4)
      Wt[((size_t)t * ND + nb + j) * KD + kb + k] = f2bf(tile[k][j]);
  }
}

// ---- MFMA GEMM over a T-chunk with reg-prefetch pipeline ----
// C[b,t,n] = relu_bn(A[b,t,:]) @ Bt[tg,n,:] + bias[tg,n]
// 1D grid; tz = bid % TC_ (== XCD round-robin -> per-t L2 locality).
// PRE_BN: block prologue computes s/sh from (bsum,bsq,bg,bb) into LDS;
// staging applies h -> relu(h*s+sh) before bf16 round.
// STATS: fp32 post-bias column sums/sqsums atomically accumulated.
template <int K_DIM, int N_DIM, int BM, int BN, int BK, int WM, int WN,
          int TA, int TO, bool A_F32, bool PRE_BN, bool STATS, bool OUT_F32,
          bool A_LOCAL, bool O_LOCAL>
__global__ __launch_bounds__(256) void gemm_k(
    const void* __restrict__ Av, const u16* __restrict__ Bt,
    const float* __restrict__ bias,
    const float* __restrict__ bsum, const float* __restrict__ bsq,
    const float* __restrict__ bg, const float* __restrict__ bb,
    void* __restrict__ Out, float* __restrict__ osum, float* __restrict__ osq,
    int t0) {
  constexpr int GX = N_DIM / BN;
  constexpr int WTM = BM / WM, WTN = BN / WN;
  constexpr int FM = WTM / 16, FN = WTN / 16;
  constexpr int LDK = BK + 8;  // +8 bf16 pad -> 2-way frag-read aliasing (free)
  constexpr int ACH = BM * BK / 8 / 256;
  constexpr int BCH = BN * BK / 8 / 256;
  __shared__ __align__(16) u16 As[BM][LDK];
  __shared__ __align__(16) u16 Bs[BN][LDK];
  __shared__ __align__(16) float sS[PRE_BN ? K_DIM : 4];
  __shared__ __align__(16) float sH[PRE_BN ? K_DIM : 4];

  const int bid = blockIdx.x;
  const int tz = bid % TC_;          // XCD id under round-robin dispatch
  const int jj = bid / TC_;
  const int bx = jj % GX, by = jj / GX;
  const int tg = t0 + tz;
  const int ta = A_LOCAL ? tz : tg;
  const int to = O_LOCAL ? tz : tg;
  const int brow0 = by * BM;
  const int bcol0 = bx * BN;
  const int tid = threadIdx.x;
  const int lane = tid & 63;
  const int wid = tid >> 6;
  const int wm = wid / WN, wn = wid % WN;

  if constexpr (PRE_BN) {
    for (int i = tid; i < K_DIM; i += 256) {
      const float m = bsum[(size_t)tg * K_DIM + i] * (1.f / B_);
      const float v = bsq[(size_t)tg * K_DIM + i] * (1.f / B_) - m * m;
      const float sc = bg[(size_t)tg * K_DIM + i] * rsqrtf(v + BN_EPS);
      sS[i] = sc;
      sH[i] = bb[(size_t)tg * K_DIM + i] - m * sc;
    }
    __syncthreads();
  }

  f32x4 acc[FM][FN] = {};
  u16x8 pa[A_F32 ? 1 : ACH];
  float4 paf[A_F32 ? 2 * ACH : 1];
  u16x8 pb[BCH];

  auto loadT = [&](int k0) {
#pragma unroll
    for (int i = 0; i < ACH; ++i) {
      const int c = tid + i * 256;
      const int row = c / (BK / 8), col = (c % (BK / 8)) * 8;
      const size_t goff = ((size_t)(brow0 + row) * TA + ta) * K_DIM + k0 + col;
      if constexpr (A_F32) {
        const float* src = (const float*)Av + goff;
        paf[2 * i] = *(const float4*)src;
        paf[2 * i + 1] = *(const float4*)(src + 4);
      } else {
        pa[i] = *(const u16x8*)((const u16*)Av + goff);
      }
    }
#pragma unroll
    for (int i = 0; i < BCH; ++i) {
      const int c = tid + i * 256;
      const int row = c / (BK / 8), col = (c % (BK / 8)) * 8;
      pb[i] = *(const u16x8*)(Bt +
               ((size_t)tg * N_DIM + bcol0 + row) * K_DIM + k0 + col);
    }
  };

  auto writeT = [&](int k0) {
#pragma unroll
    for (int i = 0; i < ACH; ++i) {
      const int c = tid + i * 256;
      const int row = c / (BK / 8), col = (c % (BK / 8)) * 8;
      u16x8 v;
      if constexpr (A_F32) {
        const float fv[8] = {paf[2*i].x, paf[2*i].y, paf[2*i].z, paf[2*i].w,
                             paf[2*i+1].x, paf[2*i+1].y, paf[2*i+1].z, paf[2*i+1].w};
#pragma unroll
        for (int q = 0; q < 8; ++q) v[q] = f2bf(fv[q]);
      } else if constexpr (PRE_BN) {
        const float4 s0v = *(const float4*)&sS[k0 + col];
        const float4 s1v = *(const float4*)&sS[k0 + col + 4];
        const float4 h0v = *(const float4*)&sH[k0 + col];
        const float4 h1v = *(const float4*)&sH[k0 + col + 4];
        const float ss[8] = {s0v.x, s0v.y, s0v.z, s0v.w, s1v.x, s1v.y, s1v.z, s1v.w};
        const float hh[8] = {h0v.x, h0v.y, h0v.z, h0v.w, h1v.x, h1v.y, h1v.z, h1v.w};
#pragma unroll
        for (int q = 0; q < 8; ++q)
          v[q] = f2bf(fmaxf(bf2f(pa[i][q]) * ss[q] + hh[q], 0.f));
      } else {
        v = pa[i];
      }
      *(u16x8*)&As[row][col] = v;
    }
#pragma unroll
    for (int i = 0; i < BCH; ++i) {
      const int c = tid + i * 256;
      const int row = c / (BK / 8), col = (c % (BK / 8)) * 8;
      *(u16x8*)&Bs[row][col] = pb[i];
    }
  };

  loadT(0);
  for (int k0 = 0; k0 < K_DIM; k0 += BK) {
    writeT(k0);                       // transform + LDS write of tile k0
    __syncthreads();
    if (k0 + BK < K_DIM) loadT(k0 + BK);  // issue next-tile loads; fly under MFMA
#pragma unroll
    for (int ks = 0; ks < BK / 32; ++ks) {
      s16x8 aF[FM], bF[FN];
#pragma unroll
      for (int m = 0; m < FM; ++m)
        aF[m] = *(const s16x8*)&As[wm * WTM + m * 16 + (lane & 15)]
                                  [ks * 32 + (lane >> 4) * 8];
#pragma unroll
      for (int n = 0; n < FN; ++n)
        bF[n] = *(const s16x8*)&Bs[wn * WTN + n * 16 + (lane & 15)]
                                  [ks * 32 + (lane >> 4) * 8];
#pragma unroll
      for (int m = 0; m < FM; ++m)
#pragma unroll
        for (int n = 0; n < FN; ++n)
          acc[m][n] = __builtin_amdgcn_mfma_f32_16x16x32_bf16(aF[m], bF[n],
                                                              acc[m][n], 0, 0, 0);
    }
    __syncthreads();
  }

  // epilogue: C/D layout col=lane&15, row=(lane>>4)*4+r (m89-verified)
  const int r0 = (lane >> 4) * 4;
  const int cl = lane & 15;
#pragma unroll
  for (int n = 0; n < FN; ++n) {
    const int ncol = bcol0 + wn * WTN + n * 16 + cl;
    const float bv = bias[(size_t)tg * N_DIM + ncol];
    float csum = 0.f, csq = 0.f;
#pragma unroll
    for (int m = 0; m < FM; ++m) {
      const int rbase = brow0 + wm * WTM + m * 16 + r0;
#pragma unroll
      for (int r = 0; r < 4; ++r) {
        const float h = acc[m][n][r] + bv;
        if constexpr (STATS) { csum += h; csq += h * h; }
        const size_t oidx = ((size_t)(rbase + r) * TO + to) * N_DIM + ncol;
        if constexpr (OUT_F32) ((float*)Out)[oidx] = h;
        else                   ((u16*)Out)[oidx] = f2bf(h);
      }
    }
    if constexpr (STATS) {
      csum += __shfl_xor(csum, 16);
      csum += __shfl_xor(csum, 32);
      csq += __shfl_xor(csq, 16);
      csq += __shfl_xor(csq, 32);
      if (lane < 16) {
        atomicAdd(&osum[(size_t)tg * N_DIM + ncol], csum);
        atomicAdd(&osq[(size_t)tg * N_DIM + ncol], csq);
      }
    }
  }
}

extern "C" void kernel_launch(void* const* d_in, const int* in_sizes, int n_in,
                              void* d_out, int out_size, void* d_ws, size_t ws_size,
                              hipStream_t stream) {
  const float* prices = (const float*)d_in[0];
  const float* bn0_g = (const float*)d_in[1];
  const float* bn0_b = (const float*)d_in[2];
  const float* W1 = (const float*)d_in[3];
  const float* b1 = (const float*)d_in[4];
  const float* bn1_g = (const float*)d_in[5];
  const float* bn1_b = (const float*)d_in[6];
  const float* W2 = (const float*)d_in[7];
  const float* b2 = (const float*)d_in[8];
  const float* bn2_g = (const float*)d_in[9];
  const float* bn2_b = (const float*)d_in[10];
  const float* W3 = (const float*)d_in[11];
  const float* b3 = (const float*)d_in[12];
  (void)in_sizes; (void)n_in; (void)out_size;

  if (ws_size < 115343360ull) return;  // needs ~105 MB

  char* ws = (char*)d_ws;
  size_t off = 0;
  auto alloc = [&](size_t bytes) -> void* {
    void* p = ws + off;
    off += (bytes + 255) & ~(size_t)255;
    return p;
  };
  // stats accumulators first (contiguous -> one memset)
  float* sum0 = (float*)alloc(T_ * P_ * 4);
  float* sq0 = (float*)alloc(T_ * P_ * 4);
  float* sum1 = (float*)alloc(T_ * H1_ * 4);
  float* sq1 = (float*)alloc(T_ * H1_ * 4);
  float* sum2 = (float*)alloc(T_ * H2_ * 4);
  float* sq2 = (float*)alloc(T_ * H2_ * 4);
  const size_t statsBytes = off;
  float* s0 = (float*)alloc(T_ * P_ * 4);
  float* sh0 = (float*)alloc(T_ * P_ * 4);
  float* b1p = (float*)alloc(T_ * H1_ * 4);
  u16* W1t = (u16*)alloc((size_t)T_ * H1_ * P_ * 2);        //  4 MB
  u16* W2t = (u16*)alloc((size_t)T_ * H1_ * H2_ * 2);       // 32 MB
  u16* W3t = (u16*)alloc((size_t)T_ * H2_ * P_ * 2);        //  4 MB
  u16* h1c = (u16*)alloc((size_t)B_ * TC_ * H1_ * 2);       // 32 MB
  u16* h2c = (u16*)alloc((size_t)B_ * TC_ * H2_ * 2);       // 32 MB

  hipMemsetAsync(d_ws, 0, statsBytes, stream);

  stats0_k<<<dim3(T_, 8), 256, 0, stream>>>(prices, sum0, sq0);
  finalize_k<<<(T_ * P_ + 255) / 256, 256, 0, stream>>>(sum0, sq0, bn0_g, bn0_b,
                                                        s0, sh0, T_ * P_);
  fold1_k<<<dim3(T_, H1_ / 256), 256, 0, stream>>>(W1, b1, s0, sh0, W1t, b1p);
  castWT_k<H1_, H2_><<<dim3(H2_ / 64, H1_ / 64, T_), 256, 0, stream>>>(W2, W2t);
  castWT_k<H2_, P_><<<dim3(P_ / 64, H2_ / 64, T_), 256, 0, stream>>>(W3, W3t);

  for (int c = 0; c < T_ / TC_; ++c) {
    const int t0 = c * TC_;
    // GEMM1: prices(f32, global t) @ W1t + b1' -> h1c (bf16, local) + bn1 stats
    gemm_k<P_, H1_, 128, 128, 64, 2, 2, T_, TC_, true, false, true, false, false, true>
        <<<(H1_ / 128) * (B_ / 128) * TC_, 256, 0, stream>>>(
            prices, W1t, b1p, nullptr, nullptr, nullptr, nullptr,
            h1c, sum1, sq1, t0);
    // GEMM2: relu(bn1(h1c)) @ W2t + b2 -> h2c (bf16, local) + bn2 stats
    gemm_k<H1_, H2_, 128, 128, 64, 2, 2, TC_, TC_, false, true, true, false, true, true>
        <<<(H2_ / 128) * (B_ / 128) * TC_, 256, 0, stream>>>(
            h1c, W2t, b2, sum1, sq1, bn1_g, bn1_b, h2c, sum2, sq2, t0);
    // GEMM3: relu(bn2(h2c)) @ W3t + b3 -> out (f32, global t)
    gemm_k<H2_, P_, 64, 64, 64, 2, 2, TC_, T_, false, true, false, true, true, false>
        <<<(P_ / 64) * (B_ / 64) * TC_, 256, 0, stream>>>(
            h2c, W3t, b3, sum2, sq2, bn2_g, bn2_b, d_out, nullptr, nullptr, t0);
  }
}

// Round 10
// 762.457 us; speedup vs baseline: 1.7967x; 1.0942x over previous
//
#include <hip/hip_runtime.h>
#include <hip/hip_bf16.h>
#include <stdint.h>

// B=4096, T=64, P=64, H1=H2=512. Per-t MLP with training-mode BatchNorm.
// T chunked by TC=8 (BN stats independent per t). BN0 folded into W1/b1.
// BN1/BN2 stats from fp32 MFMA accumulators via epilogue atomics; BN
// finalize in consuming GEMM prologue; BN+ReLU fused in A-staging.
// GEMM: A reg-staged (transform) into XOR-swizzled LDS; B via
// global_load_lds width-16 (linear LDS dest + inverse-swizzled global
// source + swizzled ds_read; rule #21), double-buffered. Per-t XCD mapping.

#define B_ 4096
#define T_ 64
#define P_ 64
#define H1_ 512
#define H2_ 512
#define TC_ 8
#define BN_EPS 1e-3f

typedef float f32x4 __attribute__((ext_vector_type(4)));
typedef short s16x8 __attribute__((ext_vector_type(8)));
typedef unsigned short u16;
typedef unsigned short u16x8 __attribute__((ext_vector_type(8)));

__device__ __forceinline__ u16 f2bf(float f) {
  union { float f; unsigned u; } x; x.f = f;
  unsigned r = x.u + 0x7fffu + ((x.u >> 16) & 1u);  // RNE
  return (u16)(r >> 16);
}
__device__ __forceinline__ float bf2f(u16 h) {
  union { unsigned u; float f; } x; x.u = ((unsigned)h) << 16;
  return x.f;
}

// async global->LDS, 16B per lane; LDS dest is wave-uniform base (+lane*16 in HW)
__device__ __forceinline__ void gl2lds16(const u16* g, u16* l) {
  auto gp = reinterpret_cast<const __attribute__((address_space(1))) uint32_t*>(
      reinterpret_cast<uintptr_t>(g));
  auto lp = reinterpret_cast<__attribute__((address_space(3))) uint32_t*>(
      reinterpret_cast<uintptr_t>(l));
  __builtin_amdgcn_global_load_lds(gp, lp, 16, 0, 0);
}

// swizzled u16 index for logical (row, colbyte) in a [rows][128B] tile
__device__ __forceinline__ int swz(int row, int colbyte) {
  return (row << 6) + ((colbyte ^ ((row & 7) << 4)) >> 1);
}

// ---- BN0 stats: column reduction over B of prices[B][T*P] ----
__global__ void stats0_k(const float* __restrict__ x, float* __restrict__ sum,
                         float* __restrict__ sq) {
  const int col4 = blockIdx.x * 256 + threadIdx.x;  // 0..1023 float4-columns
  const int r0 = blockIdx.y * 64;
  const float* src = x + (size_t)r0 * (T_ * P_) + col4 * 4;
  f32x4 s = {0.f, 0.f, 0.f, 0.f}, q = {0.f, 0.f, 0.f, 0.f};
#pragma unroll 4
  for (int r = 0; r < 64; ++r) {
    const f32x4 v = *(const f32x4*)(src + (size_t)r * (T_ * P_));
    s += v;
    q += v * v;
  }
#pragma unroll
  for (int j = 0; j < 4; ++j) {
    atomicAdd(&sum[col4 * 4 + j], s[j]);
    atomicAdd(&sq[col4 * 4 + j], q[j]);
  }
}

// ---- fold BN0 into W1 (BN0 finalize inlined): W1t[t,h,p]=bf16(s0*W1);
//      b1p = b1 + sh0 @ W1 ----
__global__ void fold1_k(const float* __restrict__ W1, const float* __restrict__ b1,
                        const float* __restrict__ sum0, const float* __restrict__ sq0,
                        const float* __restrict__ g0, const float* __restrict__ bb0,
                        u16* __restrict__ W1t, float* __restrict__ b1p) {
  const int t = blockIdx.x;
  const int tid = threadIdx.x;
  __shared__ float s0l[P_], sh0l[P_];
  if (tid < P_) {
    const float m = sum0[t * P_ + tid] * (1.f / B_);
    const float v = sq0[t * P_ + tid] * (1.f / B_) - m * m;
    const float sc = g0[t * P_ + tid] * rsqrtf(v + BN_EPS);
    s0l[tid] = sc;
    sh0l[tid] = bb0[t * P_ + tid] - m * sc;
  }
  __syncthreads();
  const int h = blockIdx.y * 256 + tid;
  float acc = b1[t * H1_ + h];
  for (int p = 0; p < P_; ++p) {
    const float w = W1[((size_t)t * P_ + p) * H1_ + h];
    acc += sh0l[p] * w;
    W1t[((size_t)t * H1_ + h) * P_ + p] = f2bf(w * s0l[p]);
  }
  b1p[t * H1_ + h] = acc;
}

// ---- transpose+cast weights: Wt[t,n,k] = bf16(W[t,k,n]) ----
template <int KD, int ND>
__global__ void castWT_k(const float* __restrict__ W, u16* __restrict__ Wt) {
  const int t = blockIdx.z;
  const int kb = blockIdx.y * 64;
  const int nb = blockIdx.x * 64;
  __shared__ float tile[64][65];
  const int tid = threadIdx.x;
  {
    const int n = tid & 63, k0 = tid >> 6;
    for (int i = k0; i < 64; i += 4)
      tile[i][n] = W[((size_t)t * KD + kb + i) * ND + nb + n];
  }
  __syncthreads();
  {
    const int k = tid & 63, n0 = tid >> 6;
    for (int j = n0; j < 64; j += 4)
      Wt[((size_t)t * ND + nb + j) * KD + kb + k] = f2bf(tile[k][j]);
  }
}

// ---- MFMA GEMM over a T-chunk ----
// A reg-staged (+BN/ReLU/cast) -> swizzled LDS; B async global_load_lds with
// inverse-swizzled source, double-buffered. 1D grid, tz = bid % TC_.
template <int K_DIM, int N_DIM, int BM, int BN, int WM, int WN,
          int TA, int TO, bool A_F32, bool PRE_BN, bool STATS, bool OUT_F32,
          bool A_LOCAL, bool O_LOCAL>
__global__ __launch_bounds__(256) void gemm_k(
    const void* __restrict__ Av, const u16* __restrict__ Bt,
    const float* __restrict__ bias,
    const float* __restrict__ bsum, const float* __restrict__ bsq,
    const float* __restrict__ bg, const float* __restrict__ bb,
    void* __restrict__ Out, float* __restrict__ osum, float* __restrict__ osq,
    int t0) {
  constexpr int BK = 64;
  constexpr int GX = N_DIM / BN;
  constexpr int WTM = BM / WM, WTN = BN / WN;
  constexpr int FM = WTM / 16, FN = WTN / 16;
  constexpr int ACH = BM * 8 / 256;    // A 16B-chunks per thread
  constexpr int NCH = BN * 128 / 1024; // B 1024B wave-chunks per tile
  __shared__ __align__(16) u16 AsL[BM * 64];
  __shared__ __align__(16) u16 BsL[2][BN * 64];
  __shared__ __align__(16) float sS[PRE_BN ? K_DIM : 4];
  __shared__ __align__(16) float sH[PRE_BN ? K_DIM : 4];

  const int bid = blockIdx.x;
  const int tz = bid % TC_;  // XCD id under round-robin dispatch
  const int jj = bid / TC_;
  const int bx = jj % GX, by = jj / GX;
  const int tg = t0 + tz;
  const int ta = A_LOCAL ? tz : tg;
  const int to = O_LOCAL ? tz : tg;
  const int brow0 = by * BM;
  const int bcol0 = bx * BN;
  const int tid = threadIdx.x;
  const int lane = tid & 63;
  const int wid = tid >> 6;
  const int wm = wid / WN, wn = wid % WN;

  if constexpr (PRE_BN) {
    for (int i = tid; i < K_DIM; i += 256) {
      const float m = bsum[(size_t)tg * K_DIM + i] * (1.f / B_);
      const float v = bsq[(size_t)tg * K_DIM + i] * (1.f / B_) - m * m;
      const float sc = bg[(size_t)tg * K_DIM + i] * rsqrtf(v + BN_EPS);
      sS[i] = sc;
      sH[i] = bb[(size_t)tg * K_DIM + i] - m * sc;
    }
    __syncthreads();
  }

  f32x4 acc[FM][FN] = {};
  u16x8 pa[A_F32 ? 1 : ACH];
  float4 paf[A_F32 ? 2 * ACH : 1];

  auto loadA = [&](int k0) {
#pragma unroll
    for (int i = 0; i < ACH; ++i) {
      const int c = tid + i * 256;
      const int row = c >> 3, col = (c & 7) * 8;
      const size_t goff = ((size_t)(brow0 + row) * TA + ta) * K_DIM + k0 + col;
      if constexpr (A_F32) {
        const float* src = (const float*)Av + goff;
        paf[2 * i] = *(const float4*)src;
        paf[2 * i + 1] = *(const float4*)(src + 4);
      } else {
        pa[i] = *(const u16x8*)((const u16*)Av + goff);
      }
    }
  };

  // B: per-lane inverse-swizzled global source, linear LDS dest (rule #21)
  const int rsub = lane >> 3;
  const int koffB = ((lane & 7) ^ rsub) * 8;
  auto issueB = [&](int k0, int buf) {
    const u16* gbase =
        Bt + ((size_t)tg * N_DIM + bcol0) * K_DIM + k0 + koffB;
#pragma unroll
    for (int ch = wid; ch < NCH; ch += 4) {
      const u16* g = gbase + (size_t)(ch * 8 + rsub) * K_DIM;
      gl2lds16(g, &BsL[buf][ch * 512]);
    }
  };

  auto writeA = [&](int k0) {
#pragma unroll
    for (int i = 0; i < ACH; ++i) {
      const int c = tid + i * 256;
      const int row = c >> 3, colb = (c & 7) * 16;
      u16x8 v;
      if constexpr (A_F32) {
        const float fv[8] = {paf[2*i].x, paf[2*i].y, paf[2*i].z, paf[2*i].w,
                             paf[2*i+1].x, paf[2*i+1].y, paf[2*i+1].z, paf[2*i+1].w};
#pragma unroll
        for (int q = 0; q < 8; ++q) v[q] = f2bf(fv[q]);
      } else if constexpr (PRE_BN) {
        const int col = k0 + (c & 7) * 8;
        const float4 s0v = *(const float4*)&sS[col];
        const float4 s1v = *(const float4*)&sS[col + 4];
        const float4 h0v = *(const float4*)&sH[col];
        const float4 h1v = *(const float4*)&sH[col + 4];
        const float ss[8] = {s0v.x, s0v.y, s0v.z, s0v.w, s1v.x, s1v.y, s1v.z, s1v.w};
        const float hh[8] = {h0v.x, h0v.y, h0v.z, h0v.w, h1v.x, h1v.y, h1v.z, h1v.w};
#pragma unroll
        for (int q = 0; q < 8; ++q)
          v[q] = f2bf(fmaxf(bf2f(pa[i][q]) * ss[q] + hh[q], 0.f));
      } else {
        v = pa[i];
      }
      *(u16x8*)&AsL[swz(row, colb)] = v;
    }
  };

  loadA(0);
  issueB(0, 0);
  int cur = 0;
  for (int k0 = 0; k0 < K_DIM; k0 += BK) {
    writeA(k0);
    __syncthreads();  // drains vmcnt(0): As written, Bs[cur] DMA complete
    if (k0 + BK < K_DIM) {
      loadA(k0 + BK);
      issueB(k0 + BK, cur ^ 1);  // flies under MFMA
    }
#pragma unroll
    for (int ks = 0; ks < 2; ++ks) {
      s16x8 aF[FM], bF[FN];
#pragma unroll
      for (int m = 0; m < FM; ++m) {
        const int row = wm * WTM + m * 16 + (lane & 15);
        aF[m] = *(const s16x8*)&AsL[swz(row, ks * 64 + ((lane >> 4) << 4))];
      }
#pragma unroll
      for (int n = 0; n < FN; ++n) {
        const int row = wn * WTN + n * 16 + (lane & 15);
        bF[n] = *(const s16x8*)&BsL[cur][swz(row, ks * 64 + ((lane >> 4) << 4))];
      }
#pragma unroll
      for (int m = 0; m < FM; ++m)
#pragma unroll
        for (int n = 0; n < FN; ++n)
          acc[m][n] = __builtin_amdgcn_mfma_f32_16x16x32_bf16(aF[m], bF[n],
                                                              acc[m][n], 0, 0, 0);
    }
    __syncthreads();
    cur ^= 1;
  }

  // epilogue: C/D layout col=lane&15, row=(lane>>4)*4+r (m89-verified)
  const int r0 = (lane >> 4) * 4;
  const int cl = lane & 15;
#pragma unroll
  for (int n = 0; n < FN; ++n) {
    const int ncol = bcol0 + wn * WTN + n * 16 + cl;
    const float bv = bias[(size_t)tg * N_DIM + ncol];
    float csum = 0.f, csq = 0.f;
#pragma unroll
    for (int m = 0; m < FM; ++m) {
      const int rbase = brow0 + wm * WTM + m * 16 + r0;
#pragma unroll
      for (int r = 0; r < 4; ++r) {
        const float h = acc[m][n][r] + bv;
        if constexpr (STATS) { csum += h; csq += h * h; }
        const size_t oidx = ((size_t)(rbase + r) * TO + to) * N_DIM + ncol;
        if constexpr (OUT_F32) ((float*)Out)[oidx] = h;
        else                   ((u16*)Out)[oidx] = f2bf(h);
      }
    }
    if constexpr (STATS) {
      csum += __shfl_xor(csum, 16);
      csum += __shfl_xor(csum, 32);
      csq += __shfl_xor(csq, 16);
      csq += __shfl_xor(csq, 32);
      if (lane < 16) {
        atomicAdd(&osum[(size_t)tg * N_DIM + ncol], csum);
        atomicAdd(&osq[(size_t)tg * N_DIM + ncol], csq);
      }
    }
  }
}

extern "C" void kernel_launch(void* const* d_in, const int* in_sizes, int n_in,
                              void* d_out, int out_size, void* d_ws, size_t ws_size,
                              hipStream_t stream) {
  const float* prices = (const float*)d_in[0];
  const float* bn0_g = (const float*)d_in[1];
  const float* bn0_b = (const float*)d_in[2];
  const float* W1 = (const float*)d_in[3];
  const float* b1 = (const float*)d_in[4];
  const float* bn1_g = (const float*)d_in[5];
  const float* bn1_b = (const float*)d_in[6];
  const float* W2 = (const float*)d_in[7];
  const float* b2 = (const float*)d_in[8];
  const float* bn2_g = (const float*)d_in[9];
  const float* bn2_b = (const float*)d_in[10];
  const float* W3 = (const float*)d_in[11];
  const float* b3 = (const float*)d_in[12];
  (void)in_sizes; (void)n_in; (void)out_size;

  if (ws_size < 115343360ull) return;  // needs ~105 MB

  char* ws = (char*)d_ws;
  size_t off = 0;
  auto alloc = [&](size_t bytes) -> void* {
    void* p = ws + off;
    off += (bytes + 255) & ~(size_t)255;
    return p;
  };
  // stats accumulators first (contiguous -> one memset)
  float* sum0 = (float*)alloc(T_ * P_ * 4);
  float* sq0 = (float*)alloc(T_ * P_ * 4);
  float* sum1 = (float*)alloc(T_ * H1_ * 4);
  float* sq1 = (float*)alloc(T_ * H1_ * 4);
  float* sum2 = (float*)alloc(T_ * H2_ * 4);
  float* sq2 = (float*)alloc(T_ * H2_ * 4);
  const size_t statsBytes = off;
  float* b1p = (float*)alloc(T_ * H1_ * 4);
  u16* W1t = (u16*)alloc((size_t)T_ * H1_ * P_ * 2);        //  4 MB
  u16* W2t = (u16*)alloc((size_t)T_ * H1_ * H2_ * 2);       // 32 MB
  u16* W3t = (u16*)alloc((size_t)T_ * H2_ * P_ * 2);        //  4 MB
  u16* h1c = (u16*)alloc((size_t)B_ * TC_ * H1_ * 2);       // 32 MB
  u16* h2c = (u16*)alloc((size_t)B_ * TC_ * H2_ * 2);       // 32 MB

  (void)hipMemsetAsync(d_ws, 0, statsBytes, stream);

  stats0_k<<<dim3(4, 64), 256, 0, stream>>>(prices, sum0, sq0);
  fold1_k<<<dim3(T_, H1_ / 256), 256, 0, stream>>>(W1, b1, sum0, sq0,
                                                   bn0_g, bn0_b, W1t, b1p);
  castWT_k<H1_, H2_><<<dim3(H2_ / 64, H1_ / 64, T_), 256, 0, stream>>>(W2, W2t);
  castWT_k<H2_, P_><<<dim3(P_ / 64, H2_ / 64, T_), 256, 0, stream>>>(W3, W3t);

  for (int c = 0; c < T_ / TC_; ++c) {
    const int t0 = c * TC_;
    // GEMM1: prices(f32, global t) @ W1t + b1' -> h1c (bf16, local) + bn1 stats
    gemm_k<P_, H1_, 128, 128, 2, 2, T_, TC_, true, false, true, false, false, true>
        <<<(H1_ / 128) * (B_ / 128) * TC_, 256, 0, stream>>>(
            prices, W1t, b1p, nullptr, nullptr, nullptr, nullptr,
            h1c, sum1, sq1, t0);
    // GEMM2: relu(bn1(h1c)) @ W2t + b2 -> h2c (bf16, local) + bn2 stats
    gemm_k<H1_, H2_, 128, 128, 2, 2, TC_, TC_, false, true, true, false, true, true>
        <<<(H2_ / 128) * (B_ / 128) * TC_, 256, 0, stream>>>(
            h1c, W2t, b2, sum1, sq1, bn1_g, bn1_b, h2c, sum2, sq2, t0);
    // GEMM3: relu(bn2(h2c)) @ W3t + b3 -> out (f32, global t)
    gemm_k<H2_, P_, 64, 64, 2, 2, TC_, T_, false, true, false, true, true, false>
        <<<(P_ / 64) * (B_ / 64) * TC_, 256, 0, stream>>>(
            h2c, W3t, b3, sum2, sq2, bn2_g, bn2_b, d_out, nullptr, nullptr, t0);
  }
}